// Round 2
// baseline (645.443 us; speedup 1.0000x reference)
//
#include <hip/hip_runtime.h>

#define B_ 4
#define N_ 4096
#define ROWS (B_ * N_)            // 16384 per side
#define PTS_TOTAL (2 * ROWS)      // 32768 points
#define NBLK 512                  // grid; __launch_bounds__(256,4) => capacity 1024, all resident

#define LOG2E 1.4426950408889634f
#define LN2   0.6931471805599453f
#define NEG_LOG2M (-12.0f)              /* -log2(4096) */
#define EPS1LNM 8.317766166719343e-4f   /* eps1 * ln(4096) */

typedef _Float16 h2 __attribute__((ext_vector_type(2)));
typedef _Float16 v8h __attribute__((ext_vector_type(8)));
typedef float f32x4 __attribute__((ext_vector_type(4)));

__device__ inline float fexp2(float x) { return __builtin_amdgcn_exp2f(x); }
__device__ inline float flog2(float x) { return __builtin_amdgcn_logf(x); }

__device__ inline unsigned fenc(float f) {
  unsigned u = __float_as_uint(f);
  return (u & 0x80000000u) ? ~u : (u | 0x80000000u);
}
__device__ inline float fdec(unsigned u) {
  return (u & 0x80000000u) ? __uint_as_float(u & 0x7fffffffu)
                           : __uint_as_float(~u);
}
__device__ inline unsigned pkh2(float a, float b) {
  h2 hv; hv.x = (_Float16)a; hv.y = (_Float16)b;
  return __builtin_bit_cast(unsigned, hv);
}
__device__ inline v8h bcv8(uint4 u) { return __builtin_bit_cast(v8h, u); }

// ---- one-shot grid barrier (counter pre-zeroed by init kernel) ------------
__device__ inline void gbar(unsigned* c) {
  __threadfence();                 // publish this thread's prior writes
  __syncthreads();                 // all fences in block done
  if (threadIdx.x == 0) {
    __hip_atomic_fetch_add(c, 1u, __ATOMIC_ACQ_REL, __HIP_MEMORY_SCOPE_AGENT);
    while (__hip_atomic_load(c, __ATOMIC_ACQUIRE, __HIP_MEMORY_SCOPE_AGENT) <
           (unsigned)NBLK) {
      __builtin_amdgcn_s_sleep(1);
    }
  }
  __syncthreads();
  __threadfence();                 // invalidate stale cached lines
}

// ---- Taylor softmin evaluation (eps0 regime); M in LDS ----
__device__ inline float taylor_f(const float* __restrict__ M, const float* v,
                                 float q, float eps0) {
  float sc2 = 2.0f * LOG2E / eps0;
  float p[6];
#pragma unroll
  for (int d = 0; d < 6; ++d) p[d] = v[d] * sc2;
  float t1 = 0.0f;
#pragma unroll
  for (int d = 0; d < 6; ++d) t1 += p[d] * M[1 + d];
  float t2 = 0.0f;
  int kk = 7;
#pragma unroll
  for (int d = 0; d < 6; ++d) {
#pragma unroll
    for (int e = d; e < 6; ++e) {
      float coef = (d == e) ? 1.0f : 2.0f;
      t2 += coef * p[d] * p[e] * M[kk];
      kk++;
    }
  }
  float S = M[0] + LN2 * t1 + (0.5f * LN2 * LN2) * t2;
  return q - eps0 * LN2 * flog2(S);
}

// ---- weighted-moment block reduce: 28 partials -> dst[0..27] --------------
__device__ inline void mom_reduce(float wgt, const float* v,
                                  float* __restrict__ dst,
                                  float (*shf)[28], int t, int wave, int lane) {
  float acc[28];
  acc[0] = wgt;
  int kk = 1;
#pragma unroll
  for (int d = 0; d < 6; ++d) acc[kk++] = wgt * v[d];
#pragma unroll
  for (int d = 0; d < 6; ++d) {
    float wv = wgt * v[d];
#pragma unroll
    for (int e = d; e < 6; ++e) acc[kk++] = wv * v[e];
  }
#pragma unroll
  for (int off = 32; off > 0; off >>= 1) {
#pragma unroll
    for (int k = 0; k < 28; ++k) acc[k] += __shfl_xor(acc[k], off);
  }
  if (lane == 0) {
#pragma unroll
    for (int k = 0; k < 28; ++k) shf[wave][k] = acc[k];
  }
  __syncthreads();
  if (t < 28) {
    dst[t] = (shf[0][t] + shf[1][t]) + (shf[2][t] + shf[3][t]);
  }
}

// ---- eps1 softmin pass via MFMA for one 32-row group ----------------------
__device__ inline void softmax_pass(int vb, const uint4* __restrict__ AREC,
                                    const uint4* __restrict__ BIN,
                                    uint4* __restrict__ BOUT,
                                    const float* __restrict__ Qarr,
                                    const float* __restrict__ prev,
                                    float* __restrict__ part,
                                    float (*lm)[32], float* fsh) {
  int t = threadIdx.x;
  int wave = t >> 6, lane = t & 63;
  int l16 = lane & 15;
  bool ldq = lane < 16;                       // quad 0 carries k=0..7
  int grow0 = vb * 32;                        // 32 rows per group
  int side = grow0 >> 14;
  int batch = (grow0 & (ROWS - 1)) >> 12;
  int colrec0 = (side ^ 1) * ROWS + batch * 4096 + wave * 1024;

  uint4 z4 = (uint4){0u, 0u, 0u, 0u};
  uint4 a1u = z4, a2u = z4;
  if (ldq) {
    a1u = AREC[grow0 + l16];
    a2u = AREC[grow0 + 16 + l16];
  }
  v8h a1 = bcv8(a1u), a2 = bcv8(a2u);

  f32x4 m2a = {-3.0e38f, -3.0e38f, -3.0e38f, -3.0e38f};
  f32x4 m2b = m2a;
  const f32x4 cz = {0.0f, 0.0f, 0.0f, 0.0f};

#pragma unroll 4
  for (int tt = 0; tt < 64; ++tt) {
    uint4 bu = z4;
    if (ldq) bu = BIN[colrec0 + tt * 16 + l16];
    v8h b = bcv8(bu);
    f32x4 d1 = __builtin_amdgcn_mfma_f32_16x16x32_f16(a1, b, cz, 0, 0, 0);
    f32x4 d2 = __builtin_amdgcn_mfma_f32_16x16x32_f16(a2, b, cz, 0, 0, 0);
    m2a = __builtin_elementwise_max(m2a, d1);
    m2b = __builtin_elementwise_max(m2b, d2);
  }

  // reduce over the 16 col-lanes (C/D: col=lane&15, row=quad*4+reg)
#pragma unroll
  for (int off = 1; off <= 8; off <<= 1) {
#pragma unroll
    for (int r = 0; r < 4; ++r) {
      m2a[r] = fmaxf(m2a[r], __shfl_xor(m2a[r], off));
      m2b[r] = fmaxf(m2b[r], __shfl_xor(m2b[r], off));
    }
  }

  if (l16 == 0) {
    int qd = lane >> 4;
#pragma unroll
    for (int r = 0; r < 4; ++r) {
      lm[wave][qd * 4 + r] = m2a[r];
      lm[wave][16 + qd * 4 + r] = m2b[r];
    }
  }
  __syncthreads();
  if (t < 32) {
    int gg = grow0 + t;
    float m = fmaxf(fmaxf(lm[0][t], lm[1][t]), fmaxf(lm[2][t], lm[3][t]));
    float qv = Qarr[gg];
    float f_t = qv - 2.0f * m;
    float fo = prev ? 0.5f * (prev[gg] + f_t) : f_t;
    if (BOUT) {
      float hs = 0.5f * (fo - qv - EPS1LNM);
      uint4 ar = AREC[gg];
      BOUT[gg] = (uint4){ar.x, ar.y, ar.z, pkh2(hs, 0.0f)};
    }
    if (part) {
      fsh[t] = fo;
      __builtin_amdgcn_s_waitcnt(0);  // lgkm drain within wave
      if (t == 0) {
        float ssum = 0.0f;
#pragma unroll
        for (int k = 0; k < 32; ++k) ssum += fsh[k];
        part[vb] = ssum;
      }
    }
  }
  __syncthreads();   // protect lm/fsh before next virtual group reuses them
}

// ==== K0: zero the 8 one-shot barrier counters =============================
__global__ void init_kernel(unsigned* barc) {
  if (threadIdx.x < 8) barc[threadIdx.x] = 0u;
}

// ==== single fused kernel (plain launch, own barriers) =====================
__global__ __launch_bounds__(256, 4) void fused_kernel(
    const float* __restrict__ x, const float* __restrict__ y,
    float* __restrict__ out, float* __restrict__ w) {
  const int t = threadIdx.x;
  const int wave = t >> 6, lane = t & 63;
  const int bx = blockIdx.x;
  const bool rowblk = bx < 128;

  // workspace layout (floats)
  unsigned* BARC = (unsigned*)w;                    // 8 counters
  unsigned* RMAXu = (unsigned*)w + 64;              // [128*16] block maxes
  float* MOMP1 = w + 2560;                          // [128*32]
  float* MOMP2 = w + 2560 + 4096;                   // [128*32]
  float* base  = w + 16384;
  uint4* AREC  = (uint4*)base;                      // 32768 recs
  uint4* BRECA = AREC + PTS_TOTAL;
  uint4* BRECB = BRECA + PTS_TOTAL;
  float* Qarr  = base + 3 * (PTS_TOTAL * 4);
  float* FG2   = Qarr + PTS_TOTAL;
  float* PART  = FG2 + PTS_TOTAL;                   // 1024

  __shared__ unsigned shu[4][13];
  __shared__ float shf[4][28];
  __shared__ float Msh[28];
  __shared__ float lm[4][32];
  __shared__ float fsh[32];

  // live-across-phase registers (rowblk only)
  float d[6];
  float vv[6], qv = 0.0f, eps0 = 0.0f, f1 = 0.0f;
  const int g = bx * 256 + t;
  const int side = g >> 14;
  const int batch = (g & (ROWS - 1)) >> 12;

  // ==== phase 1: per-block 13 flip-encoded maxes ===========================
  if (rowblk) {
    bool isx = g < ROWS;
    const float* p = (isx ? x : y) + (size_t)(isx ? g : g - ROWS) * 6;
#pragma unroll
    for (int k = 0; k < 6; ++k) d[k] = p[k];
    unsigned e[13];
    e[0] = fenc(d[0] * d[0] + d[1] * d[1] + d[2] * d[2]);
#pragma unroll
    for (int k = 0; k < 6; ++k) {
      e[1 + k] = fenc(d[k]);
      e[7 + k] = fenc(-d[k]);
    }
#pragma unroll
    for (int off = 32; off > 0; off >>= 1) {
#pragma unroll
      for (int k = 0; k < 13; ++k) {
        unsigned o = (unsigned)__shfl_xor((int)e[k], off);
        e[k] = e[k] > o ? e[k] : o;
      }
    }
    if (lane == 0) {
#pragma unroll
      for (int k = 0; k < 13; ++k) shu[wave][k] = e[k];
    }
    __syncthreads();
    if (t < 13) {
      unsigned v = shu[0][t];
#pragma unroll
      for (int wv = 1; wv < 4; ++wv) v = v > shu[wv][t] ? v : shu[wv][t];
      RMAXu[bx * 16 + t] = v;
    }
  }
  gbar(BARC + 0);

  // ==== phase 2: global maxes + pack + moment-1 partials ===================
  if (rowblk) {
    if (t < 128) {   // waves 0,1 reduce the 128 partial max sets
      unsigned e13[13];
#pragma unroll
      for (int k = 0; k < 13; ++k) e13[k] = RMAXu[t * 16 + k];
#pragma unroll
      for (int off = 32; off > 0; off >>= 1) {
#pragma unroll
        for (int k = 0; k < 13; ++k) {
          unsigned o = (unsigned)__shfl_xor((int)e13[k], off);
          e13[k] = e13[k] > o ? e13[k] : o;
        }
      }
      if (lane == 0) {
#pragma unroll
        for (int k = 0; k < 13; ++k) shu[wave][k] = e13[k];
      }
    }
    __syncthreads();
    unsigned m0 = shu[0][0] > shu[1][0] ? shu[0][0] : shu[1][0];
    float s = 1.0f / (sqrtf(fdec(m0)) + 1e-6f);
    eps0 = 0.0f;
#pragma unroll
    for (int k = 0; k < 6; ++k) {
      unsigned ma = shu[0][1 + k] > shu[1][1 + k] ? shu[0][1 + k] : shu[1][1 + k];
      unsigned mb = shu[0][7 + k] > shu[1][7 + k] ? shu[0][7 + k] : shu[1][7 + k];
      float dd = fdec(ma) + fdec(mb);
      eps0 += dd * dd;
    }

    vv[0] = d[0] * s; vv[1] = d[1] * s; vv[2] = d[2] * s;
    vv[3] = 0.1f * fminf(fmaxf(d[3], 0.0f), 1.0f);
    vv[4] = 0.1f * fminf(fmaxf(d[4], 0.0f), 1.0f);
    vv[5] = 0.1f * fminf(fmaxf(d[5], 0.0f), 1.0f);
    qv = vv[0]*vv[0] + vv[1]*vv[1] + vv[2]*vv[2] +
         vv[3]*vv[3] + vv[4]*vv[4] + vv[5]*vv[5];
    Qarr[g] = qv;
    unsigned w01 = pkh2(vv[0], vv[1]), w23 = pkh2(vv[2], vv[3]),
             w45 = pkh2(vv[4], vv[5]);
    AREC[g]  = (uint4){w01, w23, w45, pkh2(1.0f, 0.0f)};
    BRECA[g] = (uint4){w01, w23, w45, 0u};

    float wgt = fexp2(NEG_LOG2M - qv * (LOG2E / eps0));
    mom_reduce(wgt, vv, MOMP1 + (size_t)bx * 32, shf, t, wave, lane);
  }
  gbar(BARC + 1);

  // ==== phase 3: rows pair-1 (f1 in register) + moment-2 partials ==========
  if (rowblk) {
    if (t < 28) {
      const float* mp = MOMP1 + ((size_t)((side ^ 1) * 64 + batch * 16)) * 32 + t;
      float m = 0.0f;
#pragma unroll
      for (int j = 0; j < 16; ++j) m += mp[j * 32];
      Msh[t] = m;
    }
    __syncthreads();
    f1 = taylor_f(Msh, vv, qv, eps0);
    float w2 = fexp2(NEG_LOG2M + (f1 - qv) * (LOG2E / eps0));
    mom_reduce(w2, vv, MOMP2 + (size_t)bx * 32, shf, t, wave, lane);
  }
  gbar(BARC + 2);

  // ==== phase 4: rows pair-2 -> FG2 + hs2 into BRECA.w =====================
  if (rowblk) {
    if (t < 28) {
      const float* mp = MOMP2 + ((size_t)((side ^ 1) * 64 + batch * 16)) * 32 + t;
      float m = 0.0f;
#pragma unroll
      for (int j = 0; j < 16; ++j) m += mp[j * 32];
      Msh[t] = m;
    }
    __syncthreads();
    float f_t = taylor_f(Msh, vv, qv, eps0);
    float f2v = 0.5f * (f1 + f_t);
    FG2[g] = f2v;
    float hs2 = 0.5f * (f2v - qv - EPS1LNM);
    ((unsigned*)BRECA)[4 * (size_t)g + 3] = pkh2(hs2, 0.0f);
  }
  gbar(BARC + 3);

  // ==== phase 5: eps1 softmin pair-3 -> BRECB ==============================
#pragma unroll
  for (int i = 0; i < 2; ++i)
    softmax_pass(bx * 2 + i, AREC, BRECA, BRECB, Qarr, FG2, nullptr, lm, fsh);
  gbar(BARC + 4);

  // ==== phase 6: eps1 softmin pair-4 -> per-group partials =================
#pragma unroll
  for (int i = 0; i < 2; ++i)
    softmax_pass(bx * 2 + i, AREC, BRECB, nullptr, Qarr, nullptr, PART, lm, fsh);
  gbar(BARC + 5);

  // ==== phase 7: final sum =================================================
  if (bx == 0) {
    float a2 = 0.0f;
#pragma unroll
    for (int i = 0; i < 4; ++i) a2 += PART[t + i * 256];
#pragma unroll
    for (int off = 32; off > 0; off >>= 1) a2 += __shfl_xor(a2, off);
    if (lane == 0) fsh[wave] = a2;
    __syncthreads();
    if (t == 0) out[0] = (fsh[0] + fsh[1] + fsh[2] + fsh[3]) * (10.0f / (float)ROWS);
  }
}

extern "C" void kernel_launch(void* const* d_in, const int* in_sizes, int n_in,
                              void* d_out, int out_size, void* d_ws,
                              size_t ws_size, hipStream_t stream) {
  const float* x = (const float*)d_in[0];
  const float* y = (const float*)d_in[1];
  float* out = (float*)d_out;
  float* w = (float*)d_ws;
  unsigned* barc = (unsigned*)w;
  init_kernel<<<1, 64, 0, stream>>>(barc);
  fused_kernel<<<NBLK, 256, 0, stream>>>(x, y, out, w);
}

// Round 3
// 169.184 us; speedup vs baseline: 3.8150x; 3.8150x over previous
//
#include <hip/hip_runtime.h>

#define ROWS 16384                 // points per side
#define PTS_TOTAL 32768
#define NPAIR_BLK 1024             // softmin pass blocks (32 rows each)

#define LOG2E 1.4426950408889634f
#define LN2   0.6931471805599453f
#define NEG_LOG2M (-12.0f)              /* -log2(4096) */
#define EPS1LNM 8.317766166719343e-4f   /* eps1 * ln(4096) */

typedef _Float16 h2 __attribute__((ext_vector_type(2)));
typedef _Float16 v8h __attribute__((ext_vector_type(8)));
typedef float f32x4 __attribute__((ext_vector_type(4)));

__device__ inline float fexp2(float x) { return __builtin_amdgcn_exp2f(x); }
__device__ inline float flog2(float x) { return __builtin_amdgcn_logf(x); }

__device__ inline unsigned fenc(float f) {
  unsigned u = __float_as_uint(f);
  return (u & 0x80000000u) ? ~u : (u | 0x80000000u);
}
__device__ inline float fdec(unsigned u) {
  return (u & 0x80000000u) ? __uint_as_float(u & 0x7fffffffu)
                           : __uint_as_float(~u);
}
__device__ inline unsigned pkh2(float a, float b) {
  h2 hv; hv.x = (_Float16)a; hv.y = (_Float16)b;
  return __builtin_bit_cast(unsigned, hv);
}
__device__ inline v8h bcv8(uint4 u) { return __builtin_bit_cast(v8h, u); }

// ---- normalized features + squared norm (identical formulas to verified) --
__device__ inline float mkv(const float* __restrict__ p, float s, float* v) {
  v[0] = p[0] * s; v[1] = p[1] * s; v[2] = p[2] * s;
  v[3] = 0.1f * fminf(fmaxf(p[3], 0.0f), 1.0f);
  v[4] = 0.1f * fminf(fmaxf(p[4], 0.0f), 1.0f);
  v[5] = 0.1f * fminf(fmaxf(p[5], 0.0f), 1.0f);
  return v[0]*v[0] + v[1]*v[1] + v[2]*v[2] + v[3]*v[3] + v[4]*v[4] + v[5]*v[5];
}

// ---- Taylor softmin evaluation (eps0 regime); M in LDS --------------------
__device__ inline float taylor_f(const float* __restrict__ M, const float* v,
                                 float q, float eps0) {
  float sc2 = 2.0f * LOG2E / eps0;
  float p[6];
#pragma unroll
  for (int d = 0; d < 6; ++d) p[d] = v[d] * sc2;
  float t1 = 0.0f;
#pragma unroll
  for (int d = 0; d < 6; ++d) t1 += p[d] * M[1 + d];
  float t2 = 0.0f;
  int kk = 7;
#pragma unroll
  for (int d = 0; d < 6; ++d) {
#pragma unroll
    for (int e = d; e < 6; ++e) {
      float coef = (d == e) ? 1.0f : 2.0f;
      t2 += coef * p[d] * p[e] * M[kk];
      kk++;
    }
  }
  float S = M[0] + LN2 * t1 + (0.5f * LN2 * LN2) * t2;
  return q - eps0 * LN2 * flog2(S);
}

__device__ inline void accum28(float* acc, float wgt, const float* v) {
  acc[0] += wgt;
  int kk = 1;
#pragma unroll
  for (int d = 0; d < 6; ++d) acc[kk++] += wgt * v[d];
#pragma unroll
  for (int d = 0; d < 6; ++d) {
    float wv = wgt * v[d];
#pragma unroll
    for (int e = d; e < 6; ++e) acc[kk++] += wv * v[e];
  }
}

// ---- block reduce of 28 floats -> LDS dst[0..27], all-thread visible ------
__device__ inline void red28(float* acc, float* __restrict__ dst,
                             float (*shf)[28], int t, int wave, int lane) {
#pragma unroll
  for (int off = 32; off > 0; off >>= 1) {
#pragma unroll
    for (int k = 0; k < 28; ++k) acc[k] += __shfl_xor(acc[k], off);
  }
  if (lane == 0) {
#pragma unroll
    for (int k = 0; k < 28; ++k) shf[wave][k] = acc[k];
  }
  __syncthreads();
  if (t < 28) dst[t] = (shf[0][t] + shf[1][t]) + (shf[2][t] + shf[3][t]);
  __syncthreads();
}

// ==== KA: redundant scans + moment pipeline + pack (128 blocks) ============
__global__ __launch_bounds__(256) void ka_kernel(
    const float* __restrict__ x, const float* __restrict__ y,
    float* __restrict__ w) {
  const int t = threadIdx.x, wave = t >> 6, lane = t & 63;
  const int bx = blockIdx.x;
  const int g0 = bx * 256;
  const int side = g0 >> 14;
  const int batch = (g0 >> 12) & 3;

  unsigned* BARC = (unsigned*)w;
  float* base = w + 1024;
  uint4* AREC  = (uint4*)base;
  uint4* BRECA = AREC + PTS_TOTAL;
  float* Qarr  = base + 3 * 4 * PTS_TOTAL;
  float* FG2   = Qarr + PTS_TOTAL;

  __shared__ unsigned shu[4][13];
  __shared__ float shf[4][28];
  __shared__ float M1opp[28], M1own[28], M2opp[28];

  if (bx == 0 && t == 0) BARC[0] = 0u;   // collector counter for KC

  // ---- scan 1: global 13 flip-encoded maxes (all 32768 points) ----
  unsigned e[13];
#pragma unroll
  for (int k = 0; k < 13; ++k) e[k] = 0u;
  for (int srcI = 0; srcI < 2; ++srcI) {
    const float* P = srcI ? y : x;
#pragma unroll 2
    for (int i = 0; i < 64; ++i) {
      const float* p = P + (size_t)(t + i * 256) * 6;
      float dd[6];
#pragma unroll
      for (int k = 0; k < 6; ++k) dd[k] = p[k];
      unsigned c = fenc(dd[0]*dd[0] + dd[1]*dd[1] + dd[2]*dd[2]);
      e[0] = e[0] > c ? e[0] : c;
#pragma unroll
      for (int k = 0; k < 6; ++k) {
        c = fenc(dd[k]);  e[1 + k] = e[1 + k] > c ? e[1 + k] : c;
        c = fenc(-dd[k]); e[7 + k] = e[7 + k] > c ? e[7 + k] : c;
      }
    }
  }
#pragma unroll
  for (int off = 32; off > 0; off >>= 1) {
#pragma unroll
    for (int k = 0; k < 13; ++k) {
      unsigned o = (unsigned)__shfl_xor((int)e[k], off);
      e[k] = e[k] > o ? e[k] : o;
    }
  }
  if (lane == 0) {
#pragma unroll
    for (int k = 0; k < 13; ++k) shu[wave][k] = e[k];
  }
  __syncthreads();
  unsigned mm[13];
#pragma unroll
  for (int k = 0; k < 13; ++k) {
    unsigned v0 = shu[0][k] > shu[1][k] ? shu[0][k] : shu[1][k];
    unsigned v1 = shu[2][k] > shu[3][k] ? shu[2][k] : shu[3][k];
    mm[k] = v0 > v1 ? v0 : v1;
  }
  float s = 1.0f / (sqrtf(fdec(mm[0])) + 1e-6f);
  float eps0 = 0.0f;
#pragma unroll
  for (int k = 0; k < 6; ++k) {
    float dd = fdec(mm[1 + k]) + fdec(mm[7 + k]);
    eps0 += dd * dd;
  }

  const float* ptr_own = side ? y : x;
  const float* ptr_opp = side ? x : y;
  const int pb = batch * 4096;

  // ---- scan 2a: opposite panel moment-1 -> M1opp ----
  float acc[28];
#pragma unroll
  for (int k = 0; k < 28; ++k) acc[k] = 0.0f;
  for (int i = 0; i < 16; ++i) {
    const float* p = ptr_opp + (size_t)(pb + t + i * 256) * 6;
    float v[6]; float q = mkv(p, s, v);
    float wgt = fexp2(NEG_LOG2M - q * (LOG2E / eps0));
    accum28(acc, wgt, v);
  }
  red28(acc, M1opp, shf, t, wave, lane);

  // ---- scan 2b: own panel moment-1 -> M1own (needed for f1 of opp pts) ----
#pragma unroll
  for (int k = 0; k < 28; ++k) acc[k] = 0.0f;
  for (int i = 0; i < 16; ++i) {
    const float* p = ptr_own + (size_t)(pb + t + i * 256) * 6;
    float v[6]; float q = mkv(p, s, v);
    float wgt = fexp2(NEG_LOG2M - q * (LOG2E / eps0));
    accum28(acc, wgt, v);
  }
  red28(acc, M1own, shf, t, wave, lane);

  // ---- scan 3: opposite panel moment-2 (weight uses f1_j) -> M2opp ----
#pragma unroll
  for (int k = 0; k < 28; ++k) acc[k] = 0.0f;
  for (int i = 0; i < 16; ++i) {
    const float* p = ptr_opp + (size_t)(pb + t + i * 256) * 6;
    float v[6]; float q = mkv(p, s, v);
    float f1j = taylor_f(M1own, v, q, eps0);
    float w2 = fexp2(NEG_LOG2M + (f1j - q) * (LOG2E / eps0));
    accum28(acc, w2, v);
  }
  red28(acc, M2opp, shf, t, wave, lane);

  // ---- finale: own point -> f1, f2, hs2, pack records ----
  const int g = g0 + t;
  const float* p = ptr_own + (size_t)(g & (ROWS - 1)) * 6;
  float v[6]; float q = mkv(p, s, v);
  float f1 = taylor_f(M1opp, v, q, eps0);
  float f_t = taylor_f(M2opp, v, q, eps0);
  float f2 = 0.5f * (f1 + f_t);
  Qarr[g] = q;
  FG2[g] = f2;
  unsigned w01 = pkh2(v[0], v[1]), w23 = pkh2(v[2], v[3]), w45 = pkh2(v[4], v[5]);
  AREC[g] = (uint4){w01, w23, w45, pkh2(1.0f, 0.0f)};
  float hs2 = 0.5f * (f2 - q - EPS1LNM);
  BRECA[g] = (uint4){w01, w23, w45, pkh2(hs2, 0.0f)};
}

// ---- shared MFMA softmin body: returns row-max m (valid for t<32) ---------
__device__ inline float softmax_max(const uint4* __restrict__ AREC,
                                    const uint4* __restrict__ BIN,
                                    float (*lm)[32]) {
  int t = threadIdx.x;
  int wave = t >> 6, lane = t & 63;
  int l16 = lane & 15;
  bool ldq = lane < 16;                       // quad 0 carries k=0..7
  int grow0 = blockIdx.x * 32;                // 32 rows per block
  int side = grow0 >> 14;
  int batch = (grow0 & (ROWS - 1)) >> 12;
  int colrec0 = (side ^ 1) * ROWS + batch * 4096 + wave * 1024;

  uint4 z4 = (uint4){0u, 0u, 0u, 0u};
  uint4 a1u = z4, a2u = z4;
  if (ldq) {
    a1u = AREC[grow0 + l16];
    a2u = AREC[grow0 + 16 + l16];
  }
  v8h a1 = bcv8(a1u), a2 = bcv8(a2u);

  f32x4 m2a = {-3.0e38f, -3.0e38f, -3.0e38f, -3.0e38f};
  f32x4 m2b = m2a;
  const f32x4 cz = {0.0f, 0.0f, 0.0f, 0.0f};

#pragma unroll 4
  for (int tt = 0; tt < 64; ++tt) {
    uint4 bu = z4;
    if (ldq) bu = BIN[colrec0 + tt * 16 + l16];
    v8h b = bcv8(bu);
    f32x4 d1 = __builtin_amdgcn_mfma_f32_16x16x32_f16(a1, b, cz, 0, 0, 0);
    f32x4 d2 = __builtin_amdgcn_mfma_f32_16x16x32_f16(a2, b, cz, 0, 0, 0);
    m2a = __builtin_elementwise_max(m2a, d1);
    m2b = __builtin_elementwise_max(m2b, d2);
  }

  // reduce over the 16 col-lanes (C/D: col=lane&15, row=quad*4+reg)
#pragma unroll
  for (int off = 1; off <= 8; off <<= 1) {
#pragma unroll
    for (int r = 0; r < 4; ++r) {
      m2a[r] = fmaxf(m2a[r], __shfl_xor(m2a[r], off));
      m2b[r] = fmaxf(m2b[r], __shfl_xor(m2b[r], off));
    }
  }
  if (l16 == 0) {
    int qd = lane >> 4;
#pragma unroll
    for (int r = 0; r < 4; ++r) {
      lm[wave][qd * 4 + r] = m2a[r];
      lm[wave][16 + qd * 4 + r] = m2b[r];
    }
  }
  __syncthreads();
  float m = 0.0f;
  if (t < 32) m = fmaxf(fmaxf(lm[0][t], lm[1][t]), fmaxf(lm[2][t], lm[3][t]));
  return m;
}

// ==== KB: eps1 softmin pair-3 -> BRECB =====================================
__global__ __launch_bounds__(256) void kb_kernel(
    const uint4* __restrict__ AREC, const uint4* __restrict__ BIN,
    uint4* __restrict__ BOUT, const float* __restrict__ Qarr,
    const float* __restrict__ FG2) {
  __shared__ float lm[4][32];
  float m = softmax_max(AREC, BIN, lm);
  int t = threadIdx.x;
  if (t < 32) {
    int gg = blockIdx.x * 32 + t;
    float qv = Qarr[gg];
    float f_t = qv - 2.0f * m;
    float fo = 0.5f * (FG2[gg] + f_t);
    float hs = 0.5f * (fo - qv - EPS1LNM);
    uint4 ar = AREC[gg];
    BOUT[gg] = (uint4){ar.x, ar.y, ar.z, pkh2(hs, 0.0f)};
  }
}

// ==== KC: eps1 softmin pair-4 + dynamic last-block collector ===============
__global__ __launch_bounds__(256) void kc_kernel(
    const uint4* __restrict__ AREC, const uint4* __restrict__ BIN,
    const float* __restrict__ Qarr, float* __restrict__ PART,
    unsigned* __restrict__ BARC, float* __restrict__ out) {
  __shared__ float lm[4][32];
  __shared__ float fsh[32];
  __shared__ int lastf;
  float m = softmax_max(AREC, BIN, lm);
  int t = threadIdx.x;
  int wave = t >> 6, lane = t & 63;
  if (t < 32) {
    int gg = blockIdx.x * 32 + t;
    float qv = Qarr[gg];
    fsh[t] = qv - 2.0f * m;
  }
  __syncthreads();
  if (t == 0) {
    float ssum = 0.0f;
#pragma unroll
    for (int k = 0; k < 32; ++k) ssum += fsh[k];
    __hip_atomic_store(&PART[blockIdx.x], ssum, __ATOMIC_RELAXED,
                       __HIP_MEMORY_SCOPE_AGENT);
    unsigned old = __hip_atomic_fetch_add(BARC, 1u, __ATOMIC_ACQ_REL,
                                          __HIP_MEMORY_SCOPE_AGENT);
    lastf = (old == (unsigned)(NPAIR_BLK - 1)) ? 1 : 0;
  }
  __syncthreads();
  if (lastf) {  // block-uniform: only the final arriver sums and writes out
    float a = 0.0f;
#pragma unroll
    for (int i = 0; i < 4; ++i)
      a += __hip_atomic_load(&PART[t + i * 256], __ATOMIC_RELAXED,
                             __HIP_MEMORY_SCOPE_AGENT);
#pragma unroll
    for (int off = 32; off > 0; off >>= 1) a += __shfl_xor(a, off);
    if (lane == 0) fsh[wave] = a;
    __syncthreads();
    if (t == 0)
      out[0] = (fsh[0] + fsh[1] + fsh[2] + fsh[3]) * (10.0f / (float)ROWS);
  }
}

extern "C" void kernel_launch(void* const* d_in, const int* in_sizes, int n_in,
                              void* d_out, int out_size, void* d_ws,
                              size_t ws_size, hipStream_t stream) {
  const float* x = (const float*)d_in[0];
  const float* y = (const float*)d_in[1];
  float* out = (float*)d_out;
  float* w = (float*)d_ws;

  unsigned* BARC = (unsigned*)w;
  float* base = w + 1024;
  uint4* AREC  = (uint4*)base;
  uint4* BRECA = AREC + PTS_TOTAL;
  uint4* BRECB = BRECA + PTS_TOTAL;
  float* Qarr  = base + 3 * 4 * PTS_TOTAL;
  float* FG2   = Qarr + PTS_TOTAL;
  float* PART  = FG2 + PTS_TOTAL;

  ka_kernel<<<128, 256, 0, stream>>>(x, y, w);
  kb_kernel<<<NPAIR_BLK, 256, 0, stream>>>(AREC, BRECA, BRECB, Qarr, FG2);
  kc_kernel<<<NPAIR_BLK, 256, 0, stream>>>(AREC, BRECB, Qarr, PART, BARC, out);
}

// Round 4
// 127.291 us; speedup vs baseline: 5.0706x; 1.3291x over previous
//
#include <hip/hip_runtime.h>

#define ROWS 16384                 // points per side
#define PTS_TOTAL 32768
#define NSM_BLK 512                // softmin blocks, 64 rows each

#define LOG2E 1.4426950408889634f
#define LN2   0.6931471805599453f
#define NEG_LOG2M (-12.0f)              /* -log2(4096) */
#define EPS1LNM 8.317766166719343e-4f   /* eps1 * ln(4096) */

typedef _Float16 h2 __attribute__((ext_vector_type(2)));
typedef _Float16 v8h __attribute__((ext_vector_type(8)));
typedef float f32x4 __attribute__((ext_vector_type(4)));

__device__ inline float fexp2(float x) { return __builtin_amdgcn_exp2f(x); }
__device__ inline float flog2(float x) { return __builtin_amdgcn_logf(x); }

__device__ inline unsigned fenc(float f) {
  unsigned u = __float_as_uint(f);
  return (u & 0x80000000u) ? ~u : (u | 0x80000000u);
}
__device__ inline float fdec(unsigned u) {
  return (u & 0x80000000u) ? __uint_as_float(u & 0x7fffffffu)
                           : __uint_as_float(~u);
}
__device__ inline unsigned pkh2(float a, float b) {
  h2 hv; hv.x = (_Float16)a; hv.y = (_Float16)b;
  return __builtin_bit_cast(unsigned, hv);
}
__device__ inline v8h bcv8(uint4 u) { return __builtin_bit_cast(v8h, u); }

// ---- normalized features + squared norm -----------------------------------
__device__ inline float mkv(const float* __restrict__ p, float s, float* v) {
  v[0] = p[0] * s; v[1] = p[1] * s; v[2] = p[2] * s;
  v[3] = 0.1f * fminf(fmaxf(p[3], 0.0f), 1.0f);
  v[4] = 0.1f * fminf(fmaxf(p[4], 0.0f), 1.0f);
  v[5] = 0.1f * fminf(fmaxf(p[5], 0.0f), 1.0f);
  return v[0]*v[0] + v[1]*v[1] + v[2]*v[2] + v[3]*v[3] + v[4]*v[4] + v[5]*v[5];
}

// ---- Taylor softmin evaluation (eps0 regime); M in LDS --------------------
__device__ inline float taylor_f(const float* __restrict__ M, const float* v,
                                 float q, float eps0) {
  float sc2 = 2.0f * LOG2E / eps0;
  float p[6];
#pragma unroll
  for (int d = 0; d < 6; ++d) p[d] = v[d] * sc2;
  float t1 = 0.0f;
#pragma unroll
  for (int d = 0; d < 6; ++d) t1 += p[d] * M[1 + d];
  float t2 = 0.0f;
  int kk = 7;
#pragma unroll
  for (int d = 0; d < 6; ++d) {
#pragma unroll
    for (int e = d; e < 6; ++e) {
      float coef = (d == e) ? 1.0f : 2.0f;
      t2 += coef * p[d] * p[e] * M[kk];
      kk++;
    }
  }
  float S = M[0] + LN2 * t1 + (0.5f * LN2 * LN2) * t2;
  return q - eps0 * LN2 * flog2(S);
}

// ---- single-point 28-moment vector ----------------------------------------
__device__ inline void mom28(float* acc, float wgt, const float* v) {
  acc[0] = wgt;
  int kk = 1;
#pragma unroll
  for (int d = 0; d < 6; ++d) acc[kk++] = wgt * v[d];
#pragma unroll
  for (int d = 0; d < 6; ++d) {
    float wv = wgt * v[d];
#pragma unroll
    for (int e = d; e < 6; ++e) acc[kk++] = wv * v[e];
  }
}

// ---- block reduce of 28 floats -> global dst[0..27] -----------------------
__device__ inline void red28g(float* acc, float* __restrict__ dst,
                              float (*shf)[28], int t, int wave, int lane) {
#pragma unroll
  for (int off = 32; off > 0; off >>= 1) {
#pragma unroll
    for (int k = 0; k < 28; ++k) acc[k] += __shfl_xor(acc[k], off);
  }
  if (lane == 0) {
#pragma unroll
    for (int k = 0; k < 28; ++k) shf[wave][k] = acc[k];
  }
  __syncthreads();
  if (t < 28) dst[t] = (shf[0][t] + shf[1][t]) + (shf[2][t] + shf[3][t]);
}

// ---- redundant global s/eps0 from 128 max-partial sets --------------------
__device__ inline void se_from_rmax(const unsigned* __restrict__ RMAXu,
                                    unsigned (*shu)[13], float& s, float& eps0,
                                    int t, int wave, int lane) {
  int set = t & 127;   // halves duplicate a set; max is idempotent
  unsigned e[13];
#pragma unroll
  for (int k = 0; k < 13; ++k) e[k] = RMAXu[set * 16 + k];
#pragma unroll
  for (int off = 32; off > 0; off >>= 1) {
#pragma unroll
    for (int k = 0; k < 13; ++k) {
      unsigned o = (unsigned)__shfl_xor((int)e[k], off);
      e[k] = e[k] > o ? e[k] : o;
    }
  }
  if (lane == 0) {
#pragma unroll
    for (int k = 0; k < 13; ++k) shu[wave][k] = e[k];
  }
  __syncthreads();
  unsigned mm[13];
#pragma unroll
  for (int k = 0; k < 13; ++k) {
    unsigned v0 = shu[0][k] > shu[1][k] ? shu[0][k] : shu[1][k];
    unsigned v1 = shu[2][k] > shu[3][k] ? shu[2][k] : shu[3][k];
    mm[k] = v0 > v1 ? v0 : v1;
  }
  s = 1.0f / (sqrtf(fdec(mm[0])) + 1e-6f);
  eps0 = 0.0f;
#pragma unroll
  for (int k = 0; k < 6; ++k) {
    float dd = fdec(mm[1 + k]) + fdec(mm[7 + k]);
    eps0 += dd * dd;
  }
}

// ==== K1: per-block 13 max partials (1 point per thread) ===================
__global__ __launch_bounds__(256) void k1_max(
    const float* __restrict__ x, const float* __restrict__ y,
    float* __restrict__ w) {
  unsigned* BARC = (unsigned*)w;
  unsigned* RMAX = (unsigned*)w + 64;
  const int t = threadIdx.x, wave = t >> 6, lane = t & 63, bx = blockIdx.x;
  if (bx == 0 && t == 0) BARC[0] = 0u;     // collector counter for KC
  const int g = bx * 256 + t;
  bool isx = g < ROWS;
  const float* p = (isx ? x : y) + (size_t)(isx ? g : g - ROWS) * 6;
  float d[6];
#pragma unroll
  for (int k = 0; k < 6; ++k) d[k] = p[k];
  unsigned e[13];
  e[0] = fenc(d[0] * d[0] + d[1] * d[1] + d[2] * d[2]);
#pragma unroll
  for (int k = 0; k < 6; ++k) {
    e[1 + k] = fenc(d[k]);
    e[7 + k] = fenc(-d[k]);
  }
#pragma unroll
  for (int off = 32; off > 0; off >>= 1) {
#pragma unroll
    for (int k = 0; k < 13; ++k) {
      unsigned o = (unsigned)__shfl_xor((int)e[k], off);
      e[k] = e[k] > o ? e[k] : o;
    }
  }
  __shared__ unsigned shu[4][13];
  if (lane == 0) {
#pragma unroll
    for (int k = 0; k < 13; ++k) shu[wave][k] = e[k];
  }
  __syncthreads();
  if (t < 13) {
    unsigned v = shu[0][t];
#pragma unroll
    for (int wv = 1; wv < 4; ++wv) v = v > shu[wv][t] ? v : shu[wv][t];
    RMAX[bx * 16 + t] = v;
  }
}

// ==== K2: s/eps0 + pack AREC/Qarr + moment-1 partial =======================
__global__ __launch_bounds__(256) void k2_pack(
    const float* __restrict__ x, const float* __restrict__ y,
    float* __restrict__ w) {
  const int t = threadIdx.x, wave = t >> 6, lane = t & 63, bx = blockIdx.x;
  const unsigned* RMAX = (const unsigned*)w + 64;
  float* MOMP1 = w + 2560;
  float* base = w + 16384;
  uint4* AREC = (uint4*)base;
  float* Qarr = base + 3 * 4 * PTS_TOTAL;

  __shared__ unsigned shu[4][13];
  __shared__ float shf[4][28];
  float s, eps0;
  se_from_rmax(RMAX, shu, s, eps0, t, wave, lane);

  const int g = bx * 256 + t;
  const int side = g >> 14;
  const float* p = (side ? y : x) + (size_t)(g & (ROWS - 1)) * 6;
  float v[6]; float q = mkv(p, s, v);
  Qarr[g] = q;
  unsigned w01 = pkh2(v[0], v[1]), w23 = pkh2(v[2], v[3]), w45 = pkh2(v[4], v[5]);
  AREC[g] = (uint4){w01, w23, w45, pkh2(1.0f, 0.0f)};

  float wgt = fexp2(NEG_LOG2M - q * (LOG2E / eps0));
  float acc[28];
  mom28(acc, wgt, v);
  red28g(acc, MOMP1 + (size_t)bx * 32, shf, t, wave, lane);
}

// ==== K3: M1opp -> f1 (FG1) + moment-2 partial =============================
__global__ __launch_bounds__(256) void k3_rows1(
    const float* __restrict__ x, const float* __restrict__ y,
    float* __restrict__ w) {
  const int t = threadIdx.x, wave = t >> 6, lane = t & 63, bx = blockIdx.x;
  const unsigned* RMAX = (const unsigned*)w + 64;
  const float* MOMP1 = w + 2560;
  float* MOMP2 = w + 2560 + 4096;
  float* base = w + 16384;
  float* FG1 = base + 3 * 4 * PTS_TOTAL + PTS_TOTAL + PTS_TOTAL;  // after Qarr,FG2

  __shared__ unsigned shu[4][13];
  __shared__ float shf[4][28];
  __shared__ float M1opp[28];
  float s, eps0;
  se_from_rmax(RMAX, shu, s, eps0, t, wave, lane);

  const int g = bx * 256 + t;
  const int side = g >> 14;
  const int batch = (g >> 12) & 3;
  if (t < 28) {
    const float* mp = MOMP1 + ((size_t)((side ^ 1) * 64 + batch * 16)) * 32 + t;
    float m = 0.0f;
#pragma unroll
    for (int j = 0; j < 16; ++j) m += mp[j * 32];
    M1opp[t] = m;
  }
  __syncthreads();

  const float* p = (side ? y : x) + (size_t)(g & (ROWS - 1)) * 6;
  float v[6]; float q = mkv(p, s, v);
  float f1 = taylor_f(M1opp, v, q, eps0);
  FG1[g] = f1;
  float w2 = fexp2(NEG_LOG2M + (f1 - q) * (LOG2E / eps0));
  float acc[28];
  mom28(acc, w2, v);
  red28g(acc, MOMP2 + (size_t)bx * 32, shf, t, wave, lane);
}

// ==== K4: M2opp -> f2 (FG2) + BRECA with hs2 ===============================
__global__ __launch_bounds__(256) void k4_rows2(
    const float* __restrict__ x, const float* __restrict__ y,
    float* __restrict__ w) {
  const int t = threadIdx.x, wave = t >> 6, lane = t & 63, bx = blockIdx.x;
  const unsigned* RMAX = (const unsigned*)w + 64;
  const float* MOMP2 = w + 2560 + 4096;
  float* base = w + 16384;
  uint4* BRECA = (uint4*)base + PTS_TOTAL;
  float* Qarr = base + 3 * 4 * PTS_TOTAL;
  float* FG2 = Qarr + PTS_TOTAL;
  const float* FG1 = FG2 + PTS_TOTAL;

  __shared__ unsigned shu[4][13];
  __shared__ float M2opp[28];
  float s, eps0;
  se_from_rmax(RMAX, shu, s, eps0, t, wave, lane);

  const int g = bx * 256 + t;
  const int side = g >> 14;
  const int batch = (g >> 12) & 3;
  if (t < 28) {
    const float* mp = MOMP2 + ((size_t)((side ^ 1) * 64 + batch * 16)) * 32 + t;
    float m = 0.0f;
#pragma unroll
    for (int j = 0; j < 16; ++j) m += mp[j * 32];
    M2opp[t] = m;
  }
  __syncthreads();

  const float* p = (side ? y : x) + (size_t)(g & (ROWS - 1)) * 6;
  float v[6]; float q = mkv(p, s, v);
  float f1 = FG1[g];
  float f_t = taylor_f(M2opp, v, q, eps0);
  float f2 = 0.5f * (f1 + f_t);
  FG2[g] = f2;
  float hs2 = 0.5f * (f2 - q - EPS1LNM);
  unsigned w01 = pkh2(v[0], v[1]), w23 = pkh2(v[2], v[3]), w45 = pkh2(v[4], v[5]);
  BRECA[g] = (uint4){w01, w23, w45, pkh2(hs2, 0.0f)};
}

// ---- shared MFMA softmin body: 64 rows/block; row-max -> lm, valid t<64 ---
__device__ inline float softmax_max64(const uint4* __restrict__ AREC,
                                      const uint4* __restrict__ BIN,
                                      float (*lm)[64]) {
  int t = threadIdx.x;
  int wave = t >> 6, lane = t & 63;
  int l16 = lane & 15;
  bool ldq = lane < 16;                       // quad 0 carries k=0..7
  int grow0 = blockIdx.x * 64;                // 64 rows per block
  int side = grow0 >> 14;
  int batch = (grow0 & (ROWS - 1)) >> 12;
  int colrec0 = (side ^ 1) * ROWS + batch * 4096 + wave * 1024;

  uint4 z4 = (uint4){0u, 0u, 0u, 0u};
  uint4 a0u = z4, a1u = z4, a2u = z4, a3u = z4;
  if (ldq) {
    a0u = AREC[grow0 + l16];
    a1u = AREC[grow0 + 16 + l16];
    a2u = AREC[grow0 + 32 + l16];
    a3u = AREC[grow0 + 48 + l16];
  }
  v8h a0 = bcv8(a0u), a1 = bcv8(a1u), a2 = bcv8(a2u), a3 = bcv8(a3u);

  f32x4 m0 = {-3.0e38f, -3.0e38f, -3.0e38f, -3.0e38f};
  f32x4 m1 = m0, m2 = m0, m3 = m0;
  const f32x4 cz = {0.0f, 0.0f, 0.0f, 0.0f};

#pragma unroll 4
  for (int tt = 0; tt < 64; ++tt) {
    uint4 bu = z4;
    if (ldq) bu = BIN[colrec0 + tt * 16 + l16];
    v8h b = bcv8(bu);
    f32x4 d0 = __builtin_amdgcn_mfma_f32_16x16x32_f16(a0, b, cz, 0, 0, 0);
    f32x4 d1 = __builtin_amdgcn_mfma_f32_16x16x32_f16(a1, b, cz, 0, 0, 0);
    f32x4 d2 = __builtin_amdgcn_mfma_f32_16x16x32_f16(a2, b, cz, 0, 0, 0);
    f32x4 d3 = __builtin_amdgcn_mfma_f32_16x16x32_f16(a3, b, cz, 0, 0, 0);
    m0 = __builtin_elementwise_max(m0, d0);
    m1 = __builtin_elementwise_max(m1, d1);
    m2 = __builtin_elementwise_max(m2, d2);
    m3 = __builtin_elementwise_max(m3, d3);
  }

  // reduce over the 16 col-lanes (C/D: col=lane&15, row=quad*4+reg)
#pragma unroll
  for (int off = 1; off <= 8; off <<= 1) {
#pragma unroll
    for (int r = 0; r < 4; ++r) {
      m0[r] = fmaxf(m0[r], __shfl_xor(m0[r], off));
      m1[r] = fmaxf(m1[r], __shfl_xor(m1[r], off));
      m2[r] = fmaxf(m2[r], __shfl_xor(m2[r], off));
      m3[r] = fmaxf(m3[r], __shfl_xor(m3[r], off));
    }
  }
  if (l16 == 0) {
    int qd = lane >> 4;
#pragma unroll
    for (int r = 0; r < 4; ++r) {
      lm[wave][qd * 4 + r]      = m0[r];
      lm[wave][16 + qd * 4 + r] = m1[r];
      lm[wave][32 + qd * 4 + r] = m2[r];
      lm[wave][48 + qd * 4 + r] = m3[r];
    }
  }
  __syncthreads();
  float m = 0.0f;
  if (t < 64) m = fmaxf(fmaxf(lm[0][t], lm[1][t]), fmaxf(lm[2][t], lm[3][t]));
  return m;
}

// ==== KB: eps1 softmin pair-3 -> BRECB =====================================
__global__ __launch_bounds__(256) void kb_sm1(
    const uint4* __restrict__ AREC, const uint4* __restrict__ BIN,
    uint4* __restrict__ BOUT, const float* __restrict__ Qarr,
    const float* __restrict__ FG2) {
  __shared__ float lm[4][64];
  int t = threadIdx.x;
  int grow0 = blockIdx.x * 64;
  // prefetch epilogue operands; latency hides under MFMA loop
  float qv = 0.0f, fprev = 0.0f;
  uint4 ar = (uint4){0u, 0u, 0u, 0u};
  if (t < 64) {
    int gg = grow0 + t;
    qv = Qarr[gg];
    fprev = FG2[gg];
    ar = AREC[gg];
  }
  float m = softmax_max64(AREC, BIN, lm);
  if (t < 64) {
    float f_t = qv - 2.0f * m;
    float fo = 0.5f * (fprev + f_t);
    float hs = 0.5f * (fo - qv - EPS1LNM);
    BOUT[grow0 + t] = (uint4){ar.x, ar.y, ar.z, pkh2(hs, 0.0f)};
  }
}

// ==== KC: eps1 softmin pair-4 + dynamic last-block collector ===============
__global__ __launch_bounds__(256) void kc_sm2(
    const uint4* __restrict__ AREC, const uint4* __restrict__ BIN,
    const float* __restrict__ Qarr, float* __restrict__ PART,
    unsigned* __restrict__ BARC, float* __restrict__ out) {
  __shared__ float lm[4][64];
  __shared__ float fsh[64];
  __shared__ int lastf;
  int t = threadIdx.x;
  int wave = t >> 6, lane = t & 63;
  int grow0 = blockIdx.x * 64;
  float qv = 0.0f;
  if (t < 64) qv = Qarr[grow0 + t];
  float m = softmax_max64(AREC, BIN, lm);
  if (t < 64) fsh[t] = qv - 2.0f * m;
  __syncthreads();
  if (t == 0) {
    float ssum = 0.0f;
#pragma unroll
    for (int k = 0; k < 64; ++k) ssum += fsh[k];
    __hip_atomic_store(&PART[blockIdx.x], ssum, __ATOMIC_RELAXED,
                       __HIP_MEMORY_SCOPE_AGENT);
    unsigned old = __hip_atomic_fetch_add(BARC, 1u, __ATOMIC_ACQ_REL,
                                          __HIP_MEMORY_SCOPE_AGENT);
    lastf = (old == (unsigned)(NSM_BLK - 1)) ? 1 : 0;
  }
  __syncthreads();
  if (lastf) {  // block-uniform: only the final arriver sums and writes out
    float a = 0.0f;
#pragma unroll
    for (int i = 0; i < 2; ++i)
      a += __hip_atomic_load(&PART[t + i * 256], __ATOMIC_RELAXED,
                             __HIP_MEMORY_SCOPE_AGENT);
#pragma unroll
    for (int off = 32; off > 0; off >>= 1) a += __shfl_xor(a, off);
    if (lane == 0) fsh[wave] = a;
    __syncthreads();
    if (t == 0)
      out[0] = (fsh[0] + fsh[1] + fsh[2] + fsh[3]) * (10.0f / (float)ROWS);
  }
}

extern "C" void kernel_launch(void* const* d_in, const int* in_sizes, int n_in,
                              void* d_out, int out_size, void* d_ws,
                              size_t ws_size, hipStream_t stream) {
  const float* x = (const float*)d_in[0];
  const float* y = (const float*)d_in[1];
  float* out = (float*)d_out;
  float* w = (float*)d_ws;

  unsigned* BARC = (unsigned*)w;
  float* base = w + 16384;
  uint4* AREC  = (uint4*)base;
  uint4* BRECA = AREC + PTS_TOTAL;
  uint4* BRECB = BRECA + PTS_TOTAL;
  float* Qarr  = base + 3 * 4 * PTS_TOTAL;
  float* FG2   = Qarr + PTS_TOTAL;
  float* FG1   = FG2 + PTS_TOTAL;
  float* PART  = FG1 + PTS_TOTAL;

  (void)FG1; (void)ws_size;
  k1_max<<<128, 256, 0, stream>>>(x, y, w);
  k2_pack<<<128, 256, 0, stream>>>(x, y, w);
  k3_rows1<<<128, 256, 0, stream>>>(x, y, w);
  k4_rows2<<<128, 256, 0, stream>>>(x, y, w);
  kb_sm1<<<NSM_BLK, 256, 0, stream>>>(AREC, BRECA, BRECB, Qarr, FG2);
  kc_sm2<<<NSM_BLK, 256, 0, stream>>>(AREC, BRECB, Qarr, PART, BARC, out);
}